// Round 18
// baseline (477.580 us; speedup 1.0000x reference)
//
#include <hip/hip_runtime.h>
#include <hip/hip_bf16.h>

#define N_NODES 10000
#define N_EDGES 160000
#define D_IN    128
#define D_EMB   512
#define D_HID   256

typedef unsigned short u16;
typedef __attribute__((ext_vector_type(8))) short short8;
typedef __attribute__((ext_vector_type(4))) float floatx4;

__device__ __forceinline__ float bf2f(u16 u) {
    union { unsigned int i; float f; } v; v.i = ((unsigned int)u) << 16; return v.f;
}
__device__ __forceinline__ u16 f2bf(float f) {
    union { float f; unsigned int i; } v; v.f = f;
    unsigned int x = v.i;
    return (u16)((x + 0x7fffu + ((x >> 16) & 1u)) >> 16);  // RNE
}
__device__ __forceinline__ float inval(const void* p, int fp32, int idx) {
    return fp32 ? ((const float*)p)[idx] : bf2f(((const u16*)p)[idx]);
}

// async global->LDS, 16 bytes/lane; lds base must be wave-uniform.
__device__ __forceinline__ void gld_lds16(const u16* g, u16* l) {
    __builtin_amdgcn_global_load_lds((const __attribute__((address_space(1))) void*)g,
                                     (__attribute__((address_space(3))) void*)l,
                                     16, 0, 0);
}

// flag[0]: edge_index is int64-viewed-as-int32-pairs; flag[1]: floats are fp32
__device__ __forceinline__ int edge_src(const int* __restrict__ ei, int flg, int e) {
    int v = flg ? ei[2 * e] : ei[e];
    return min(max(v, 0), N_NODES - 1);
}
__device__ __forceinline__ int edge_dst(const int* __restrict__ ei, int flg, int e) {
    int v = flg ? ei[2 * N_EDGES + 2 * e] : ei[N_EDGES + e];
    return min(max(v, 0), N_NODES - 1);
}

// ---------------------------------------------------------------------------
__global__ void sentinel_kernel(float* out, int n) {
    int i = blockIdx.x * 256 + threadIdx.x;
    if (i < n) out[i] = 1.0f;   // => workspace too small
}

// detect dtypes + zero counts + zero logits + zero deg-hist, one dispatch
__global__ __launch_bounds__(256)
void detect_zero_kernel(const int* __restrict__ ei, const u16* __restrict__ xu,
                        int* flag, int* counts, float* logits, int* dhist) {
    int gid = blockIdx.x * 256 + threadIdx.x;
    for (int i = gid; i < N_NODES; i += gridDim.x * 256) { counts[i] = 0; logits[i] = 0.f; }
    if (gid < 64) dhist[gid] = 0;
    if (blockIdx.x != 0) return;
    __shared__ int s_or[256];
    __shared__ int s_cnt[256];
    int t = threadIdx.x;
    int v = 0;
    for (int k = t; k < 4096; k += 256) v |= ei[1 + 2 * k];
    int c = 0;
    for (int k = t; k < 4096; k += 256) {
        u16 u = xu[k];
        int ex = (u >> 7) & 0xFF;
        bool plaus = (u == 0) || (ex >= 64 && ex <= 191);
        if (!plaus) c++;
    }
    s_or[t] = v; s_cnt[t] = c;
    __syncthreads();
    for (int off = 128; off > 0; off >>= 1) {
        if (t < off) { s_or[t] |= s_or[t + off]; s_cnt[t] += s_cnt[t + off]; }
        __syncthreads();
    }
    if (t == 0) {
        flag[0] = (s_or[0] == 0) ? 1 : 0;
        flag[1] = (s_cnt[0] > 256) ? 1 : 0;
    }
}

// ---------------------------------------------------------------------------
// Fused preconversion; dl == nullptr -> hi only.
// ---------------------------------------------------------------------------
struct ConvJobs {
    const void* src[10];
    u16* dh[10];
    u16* dl[10];
    int rows[10], cols[10], trans[10];
    int cum[11];
    int njobs;
};

__global__ __launch_bounds__(256)
void convert_fused_kernel(ConvJobs jobs, const int* __restrict__ flag) {
    int idx = blockIdx.x * 256 + threadIdx.x;
    if (idx >= jobs.cum[jobs.njobs]) return;
    int fp32 = flag[1];
    int jb = 0;
    while (idx >= jobs.cum[jb + 1]) jb++;
    int local = idx - jobs.cum[jb];
    float v = inval(jobs.src[jb], fp32, local);
    u16 hi = f2bf(v);
    int o;
    if (jobs.trans[jb]) {
        int r = local / jobs.cols[jb], c = local % jobs.cols[jb];
        o = c * jobs.rows[jb] + r;
    } else o = local;
    jobs.dh[jb][o] = hi;
    if (jobs.dl[jb]) jobs.dl[jb][o] = f2bf(v - bf2f(hi));
}

// ---------------------------------------------------------------------------
// CSR build
// ---------------------------------------------------------------------------
__global__ void count_edges_kernel(const int* __restrict__ ei, const int* __restrict__ flag,
                                   int* counts) {
    int e = blockIdx.x * 256 + threadIdx.x;
    if (e < N_EDGES) atomicAdd(&counts[edge_dst(ei, flag[0], e)], 1);
}

__global__ __launch_bounds__(256)
void scan_counts_kernel(int* counts, int* rowptr) {
    __shared__ int part[256];
    int tid = threadIdx.x;
    const int CH = 40;
    int base = tid * CH;
    int loc[CH];
    int s = 0;
    #pragma unroll
    for (int i = 0; i < CH; i++) {
        int idx = base + i;
        int c = (idx < N_NODES) ? counts[idx] : 0;
        loc[i] = s; s += c;
    }
    part[tid] = s;
    __syncthreads();
    for (int off = 1; off < 256; off <<= 1) {
        int v = part[tid];
        int add = (tid >= off) ? part[tid - off] : 0;
        __syncthreads();
        part[tid] = v + add;
        __syncthreads();
    }
    int pre = (tid > 0) ? part[tid - 1] : 0;
    #pragma unroll
    for (int i = 0; i < CH; i++) {
        int idx = base + i;
        if (idx < N_NODES) { int v = pre + loc[i]; rowptr[idx] = v; counts[idx] = v; }
    }
    if (tid == 255) rowptr[N_NODES] = part[255];
}

__global__ void fill_esrcp_kernel(const int* __restrict__ ei, const int* __restrict__ flag,
                                  int* counts, int* esrcp) {
    int e = blockIdx.x * 256 + threadIdx.x;
    if (e < N_EDGES) {
        int flg = flag[0];
        int pos = atomicAdd(&counts[edge_dst(ei, flg, e)], 1);
        if (pos >= 0 && pos < N_EDGES) esrcp[pos] = edge_src(ei, flg, e);
    }
}

// ---------------------------------------------------------------------------
// Degree-descending node order (counting sort, 64 bins).
// After fill_esrcp: counts[n] == rowptr[n+1], so deg = counts[n]-rowptr[n].
// ---------------------------------------------------------------------------
__global__ void deg_hist_kernel(const int* __restrict__ rowptr, const int* __restrict__ counts,
                                int* dhist) {
    int n = blockIdx.x * 256 + threadIdx.x;
    if (n < N_NODES) {
        int deg = min(counts[n] - rowptr[n], 63);
        atomicAdd(&dhist[deg], 1);
    }
}

// parallel descending exclusive prefix over 64 bins (LDS-resident)
__global__ void deg_scan_kernel(int* dhist) {
    __shared__ int s[64];
    int t = threadIdx.x;                 // 64 threads
    s[t] = dhist[t];
    __syncthreads();
    int sum = 0;
    for (int b = t + 1; b < 64; b++) sum += s[b];
    dhist[t] = sum;
}

__global__ void deg_scatter_kernel(const int* __restrict__ rowptr, const int* __restrict__ counts,
                                   int* dhist, int* nodeperm) {
    int n = blockIdx.x * 256 + threadIdx.x;
    if (n < N_NODES) {
        int deg = min(counts[n] - rowptr[n], 63);
        int pos = atomicAdd(&dhist[deg], 1);
        if (pos >= 0 && pos < N_NODES) nodeperm[pos] = n;
    }
}

// ---------------------------------------------------------------------------
// Dual 128x128-tile GEMM, 2 MFMA passes, async global_load_lds staging,
// XOR-swizzled unpadded LDS. BOTH halves stored as bf16 (C0 = xl, C1 = xr).
// ---------------------------------------------------------------------------
__global__ __launch_bounds__(256)
void gemm_dual_kernel(const u16* __restrict__ Ah, const u16* __restrict__ Al,
                      const u16* __restrict__ B0h, const u16* __restrict__ B1h,
                      u16* __restrict__ C0, u16* __restrict__ C1,
                      int M, int N, int K)
{
    __shared__ u16 sAh[128 * 32];
    __shared__ u16 sAl[128 * 32];
    __shared__ u16 sBh[128 * 32];
    int nb = N >> 7;
    int half = (int)blockIdx.x >= nb;
    int bx = half ? (blockIdx.x - nb) : blockIdx.x;
    const u16* BTh = half ? B1h : B0h;
    u16* Cf = half ? C1 : C0;

    int tid = threadIdx.x;
    int lane = tid & 63, wv = tid >> 6;
    int l15 = lane & 15, l4 = lane >> 4;
    int wr = (wv >> 1) * 64, wc = (wv & 1) * 64;
    int m0 = blockIdx.y * 128, n0 = bx * 128;

    int i0 = tid, i1 = tid + 256;
    int r0 = i0 >> 2, b0 = i0 & 3, sb0 = b0 ^ ((r0 >> 1) & 3);
    int r1 = i1 >> 2, b1 = i1 & 3, sb1 = b1 ^ ((r1 >> 1) & 3);
    int gr0 = min(m0 + r0, M - 1), gr1 = min(m0 + r1, M - 1);
    const u16* a0p = Ah + (size_t)gr0 * K + sb0 * 8;
    const u16* a1p = Ah + (size_t)gr1 * K + sb1 * 8;
    const u16* l0p = Al + (size_t)gr0 * K + sb0 * 8;
    const u16* l1p = Al + (size_t)gr1 * K + sb1 * 8;
    const u16* bb0p = BTh + (size_t)(n0 + r0) * K + sb0 * 8;
    const u16* bb1p = BTh + (size_t)(n0 + r1) * K + sb1 * 8;
    u16* lA0 = &sAh[(size_t)(wv * 64) * 8];
    u16* lA1 = &sAh[(size_t)(256 + wv * 64) * 8];
    u16* lL0 = &sAl[(size_t)(wv * 64) * 8];
    u16* lL1 = &sAl[(size_t)(256 + wv * 64) * 8];
    u16* lB0 = &sBh[(size_t)(wv * 64) * 8];
    u16* lB1 = &sBh[(size_t)(256 + wv * 64) * 8];

    floatx4 acc[4][4];
    #pragma unroll
    for (int i = 0; i < 4; i++)
        #pragma unroll
        for (int j = 0; j < 4; j++) acc[i][j] = (floatx4){0.f, 0.f, 0.f, 0.f};

    int aoff[4], boff[4];
    #pragma unroll
    for (int i = 0; i < 4; i++) {
        int arow = wr + i * 16 + l15;
        aoff[i] = arow * 32 + ((l4 ^ ((arow >> 1) & 3)) << 3);
        int bcol = wc + i * 16 + l15;
        boff[i] = bcol * 32 + ((l4 ^ ((bcol >> 1) & 3)) << 3);
    }

    for (int kk = 0; kk < K; kk += 32) {
        __syncthreads();
        gld_lds16(a0p + kk, lA0);
        gld_lds16(a1p + kk, lA1);
        gld_lds16(l0p + kk, lL0);
        gld_lds16(l1p + kk, lL1);
        gld_lds16(bb0p + kk, lB0);
        gld_lds16(bb1p + kk, lB1);
        __syncthreads();

        short8 ah[4], al[4];
        #pragma unroll
        for (int i = 0; i < 4; i++) {
            ah[i] = *(const short8*)(&sAh[aoff[i]]);
            al[i] = *(const short8*)(&sAl[aoff[i]]);
        }
        #pragma unroll
        for (int j = 0; j < 4; j++) {
            short8 bh = *(const short8*)(&sBh[boff[j]]);
            #pragma unroll
            for (int i = 0; i < 4; i++) {
                acc[i][j] = __builtin_amdgcn_mfma_f32_16x16x32_bf16(ah[i], bh, acc[i][j], 0, 0, 0);
                acc[i][j] = __builtin_amdgcn_mfma_f32_16x16x32_bf16(al[i], bh, acc[i][j], 0, 0, 0);
            }
        }
    }

    #pragma unroll
    for (int j = 0; j < 4; j++) {
        int col = n0 + wc + j * 16 + l15;
        #pragma unroll
        for (int i = 0; i < 4; i++) {
            #pragma unroll
            for (int r = 0; r < 4; r++) {
                int row = m0 + wr + i * 16 + l4 * 4 + r;
                if (row < M) Cf[(size_t)row * N + col] = f2bf(acc[i][j][r]);
            }
        }
    }
}

// ---------------------------------------------------------------------------
// MLP GEMM, 64x64 tile, async staging + swizzle, bias+leaky.
// FUSE=0: store hi/lo pair. FUSE=1: fused logit GEMV via atomics (no stores).
// ---------------------------------------------------------------------------
template<int FUSE>
__global__ __launch_bounds__(256)
void gemm_mlp64_kernel(const u16* __restrict__ Ah, const u16* __restrict__ Al,
                       const u16* __restrict__ BTh,
                       u16* __restrict__ Ch, u16* __restrict__ Cl,
                       const void* __restrict__ biasraw,
                       const void* __restrict__ A3raw, float* __restrict__ logits,
                       const int* __restrict__ flag,
                       int M, int N, int K)
{
    __shared__ u16 sAh[64 * 32];
    __shared__ u16 sAl[64 * 32];
    __shared__ u16 sBh[64 * 32];
    int tid = threadIdx.x;
    int lane = tid & 63, wv = tid >> 6;
    int l15 = lane & 15, l4 = lane >> 4;
    int m0 = blockIdx.y * 64, n0 = blockIdx.x * 64;

    int r = (tid >> 2), blk = tid & 3, sb = blk ^ ((r >> 1) & 3);
    int gr = min(m0 + r, M - 1);
    const u16* ap = Ah + (size_t)gr * K + sb * 8;
    const u16* lp = Al + (size_t)gr * K + sb * 8;
    const u16* bp = BTh + (size_t)(n0 + r) * K + sb * 8;
    u16* lA = &sAh[(size_t)(wv * 64) * 8];
    u16* lL = &sAl[(size_t)(wv * 64) * 8];
    u16* lB = &sBh[(size_t)(wv * 64) * 8];

    floatx4 acc[4];
    #pragma unroll
    for (int j = 0; j < 4; j++) acc[j] = (floatx4){0.f, 0.f, 0.f, 0.f};

    int arow = wv * 16 + l15;
    int aoff = arow * 32 + ((l4 ^ ((arow >> 1) & 3)) << 3);
    int boff[4];
    #pragma unroll
    for (int j = 0; j < 4; j++) {
        int bcol = j * 16 + l15;
        boff[j] = bcol * 32 + ((l4 ^ ((bcol >> 1) & 3)) << 3);
    }

    for (int kk = 0; kk < K; kk += 32) {
        __syncthreads();
        gld_lds16(ap + kk, lA);
        gld_lds16(lp + kk, lL);
        gld_lds16(bp + kk, lB);
        __syncthreads();

        short8 ah = *(const short8*)(&sAh[aoff]);
        short8 al = *(const short8*)(&sAl[aoff]);
        #pragma unroll
        for (int j = 0; j < 4; j++) {
            short8 bh = *(const short8*)(&sBh[boff[j]]);
            acc[j] = __builtin_amdgcn_mfma_f32_16x16x32_bf16(ah, bh, acc[j], 0, 0, 0);
            acc[j] = __builtin_amdgcn_mfma_f32_16x16x32_bf16(al, bh, acc[j], 0, 0, 0);
        }
    }

    const int fp32 = flag[1];
    float lsum[4] = {0.f, 0.f, 0.f, 0.f};
    #pragma unroll
    for (int j = 0; j < 4; j++) {
        int col = n0 + j * 16 + l15;
        float bv = inval(biasraw, fp32, col);
        float a3 = FUSE ? inval(A3raw, fp32, col) : 0.f;
        #pragma unroll
        for (int rr = 0; rr < 4; rr++) {
            int row = m0 + wv * 16 + l4 * 4 + rr;
            if (row < M) {
                float v = acc[j][rr] + bv;
                v = v > 0.f ? v : 0.1f * v;
                if (FUSE) {
                    lsum[rr] += v * a3;
                } else {
                    u16 hi = f2bf(v);
                    Ch[(size_t)row * N + col] = hi;
                    Cl[(size_t)row * N + col] = f2bf(v - bf2f(hi));
                }
            }
        }
    }
    if (FUSE) {
        #pragma unroll
        for (int rr = 0; rr < 4; rr++) {
            float s = lsum[rr];
            s += __shfl_xor(s, 1);
            s += __shfl_xor(s, 2);
            s += __shfl_xor(s, 4);
            s += __shfl_xor(s, 8);
            int row = m0 + wv * 16 + l4 * 4 + rr;
            if (l15 == 0 && row < M) atomicAdd(&logits[row], s);
        }
    }
}

// ---------------------------------------------------------------------------
// GATv2: wave-per-node (degree-sorted order), single-pass online softmax,
// unroll x4. Both xl and xr gathered as bf16.
// ---------------------------------------------------------------------------
__device__ __forceinline__ void online_update(float e, const float v[8],
                                              float& m_run, float& s_run, float acc[8])
{
    if (e > m_run) {                       // lane-uniform branch
        float sc = __expf(m_run - e);
        s_run = s_run * sc + 1.f;
        #pragma unroll
        for (int k = 0; k < 8; k++) acc[k] = acc[k] * sc + v[k];
        m_run = e;
    } else {
        float w = __expf(e - m_run);
        s_run += w;
        #pragma unroll
        for (int k = 0; k < 8; k++) acc[k] += w * v[k];
    }
}

__global__ __launch_bounds__(256)
void gat_wave_kernel(const int* __restrict__ rowptr, const int* __restrict__ esrcp,
                     const int* __restrict__ nodeperm,
                     const u16* __restrict__ xlb, const u16* __restrict__ xrb,
                     const void* __restrict__ att, const void* __restrict__ bias,
                     const int* __restrict__ flag,
                     u16* __restrict__ hh, u16* __restrict__ hl)
{
    int lane = threadIdx.x & 63, wv = threadIdx.x >> 6;
    int slot = blockIdx.x * 4 + wv;
    if (slot >= N_NODES) return;
    int n = nodeperm[slot];
    int fp32 = flag[1];
    int d0 = lane * 8;

    union { uint4 q; u16 us[8]; } xru;
    xru.q = *(const uint4*)(xrb + (size_t)n * D_EMB + d0);
    float xrv[8];
    #pragma unroll
    for (int k = 0; k < 8; k++) xrv[k] = bf2f(xru.us[k]);
    float attv[8];
    #pragma unroll
    for (int k = 0; k < 8; k++) attv[k] = inval(att, fp32, d0 + k);

    int beg = rowptr[n], end = rowptr[n + 1];
    float m_run = -3.4e38f, s_run = 0.f;
    float acc[8] = {0.f, 0.f, 0.f, 0.f, 0.f, 0.f, 0.f, 0.f};

    int j = beg;
    for (; j + 4 <= end; j += 4) {
        int s0 = esrcp[j], s1 = esrcp[j + 1], s2 = esrcp[j + 2], s3 = esrcp[j + 3];
        union { uint4 q; u16 us[8]; } u0, u1, u2, u3;
        u0.q = *(const uint4*)(xlb + (size_t)s0 * D_EMB + d0);
        u1.q = *(const uint4*)(xlb + (size_t)s1 * D_EMB + d0);
        u2.q = *(const uint4*)(xlb + (size_t)s2 * D_EMB + d0);
        u3.q = *(const uint4*)(xlb + (size_t)s3 * D_EMB + d0);
        float v0[8], v1[8], v2[8], v3[8];
        #pragma unroll
        for (int k = 0; k < 8; k++) {
            v0[k] = bf2f(u0.us[k]); v1[k] = bf2f(u1.us[k]);
            v2[k] = bf2f(u2.us[k]); v3[k] = bf2f(u3.us[k]);
        }
        float e0 = 0.f, e1 = 0.f, e2 = 0.f, e3 = 0.f;
        #pragma unroll
        for (int k = 0; k < 8; k++) {
            float t0 = v0[k] + xrv[k]; t0 = t0 > 0.f ? t0 : 0.2f * t0; e0 += attv[k] * t0;
            float t1 = v1[k] + xrv[k]; t1 = t1 > 0.f ? t1 : 0.2f * t1; e1 += attv[k] * t1;
            float t2 = v2[k] + xrv[k]; t2 = t2 > 0.f ? t2 : 0.2f * t2; e2 += attv[k] * t2;
            float t3 = v3[k] + xrv[k]; t3 = t3 > 0.f ? t3 : 0.2f * t3; e3 += attv[k] * t3;
        }
        #pragma unroll
        for (int o = 32; o > 0; o >>= 1) {
            e0 += __shfl_xor(e0, o);
            e1 += __shfl_xor(e1, o);
            e2 += __shfl_xor(e2, o);
            e3 += __shfl_xor(e3, o);
        }
        online_update(e0, v0, m_run, s_run, acc);
        online_update(e1, v1, m_run, s_run, acc);
        online_update(e2, v2, m_run, s_run, acc);
        online_update(e3, v3, m_run, s_run, acc);
    }
    for (; j < end; j++) {
        int s0 = esrcp[j];
        union { uint4 q; u16 us[8]; } u0;
        u0.q = *(const uint4*)(xlb + (size_t)s0 * D_EMB + d0);
        float v0[8];
        #pragma unroll
        for (int k = 0; k < 8; k++) v0[k] = bf2f(u0.us[k]);
        float e0 = 0.f;
        #pragma unroll
        for (int k = 0; k < 8; k++) {
            float t = v0[k] + xrv[k]; t = t > 0.f ? t : 0.2f * t; e0 += attv[k] * t;
        }
        #pragma unroll
        for (int o = 32; o > 0; o >>= 1) e0 += __shfl_xor(e0, o);
        online_update(e0, v0, m_run, s_run, acc);
    }

    float inv = 1.f / (s_run + 1e-16f);
    union { uint4 q; u16 us[8]; } ph, pl;
    #pragma unroll
    for (int k = 0; k < 8; k++) {
        float h = tanhf(acc[k] * inv + inval(bias, fp32, d0 + k));
        u16 hi = f2bf(h);
        ph.us[k] = hi;
        pl.us[k] = f2bf(h - bf2f(hi));
    }
    *(uint4*)(&hh[(size_t)n * D_EMB + d0]) = ph.q;
    *(uint4*)(&hl[(size_t)n * D_EMB + d0]) = pl.q;
}

// ---------------------------------------------------------------------------
__global__ __launch_bounds__(256)
void softmax_kernel(const float* __restrict__ logits, float* __restrict__ out)
{
    __shared__ float red[4];
    __shared__ float s_m, s_s;
    int tid = threadIdx.x, lane = tid & 63, wv = tid >> 6;
    float m = -3.4e38f;
    for (int i = tid; i < N_NODES; i += 256) m = fmaxf(m, logits[i]);
    #pragma unroll
    for (int o = 32; o > 0; o >>= 1) m = fmaxf(m, __shfl_down(m, o));
    if (lane == 0) red[wv] = m;
    __syncthreads();
    if (tid == 0) {
        float mm = red[0];
        for (int i = 1; i < 4; i++) mm = fmaxf(mm, red[i]);
        s_m = mm;
    }
    __syncthreads();
    float mm = s_m;
    float s = 0.f;
    for (int i = tid; i < N_NODES; i += 256) s += __expf(logits[i] - mm);
    #pragma unroll
    for (int o = 32; o > 0; o >>= 1) s += __shfl_down(s, o);
    if (lane == 0) red[wv] = s;
    __syncthreads();
    if (tid == 0) {
        float ss = 0.f;
        for (int i = 0; i < 4; i++) ss += red[i];
        s_s = ss;
    }
    __syncthreads();
    float invs = 1.f / s_s;
    for (int i = tid; i < N_NODES; i += 256) out[i] = __expf(logits[i] - mm) * invs;
}

// ---------------------------------------------------------------------------
extern "C" void kernel_launch(void* const* d_in, const int* in_sizes, int n_in,
                              void* d_out, int out_size, void* d_ws, size_t ws_size,
                              hipStream_t stream)
{
    const void* x   = d_in[0];
    const int*  ei  = (const int*)d_in[1];
    const void* Wl[3]  = {d_in[2],  d_in[6],  d_in[10]};
    const void* Wr[3]  = {d_in[3],  d_in[7],  d_in[11]};
    const void* att[3] = {d_in[4],  d_in[8],  d_in[12]};
    const void* bia[3] = {d_in[5],  d_in[9],  d_in[13]};
    const void* A1 = d_in[14];
    const void* c1 = d_in[15];
    const void* A2 = d_in[16];
    const void* c2 = d_in[17];
    const void* A3 = d_in[18];

    char* p = (char*)d_ws;
    auto alloc = [&](size_t bytes) {
        char* r = p;
        p += (bytes + 255) & ~(size_t)255;
        return r;
    };
    u16*   xlb    = (u16*)  alloc((size_t)N_NODES * D_EMB * 4);   // bf16 xl (first half) + MLP aliases
    u16*   xrb    = (u16*)  alloc((size_t)N_NODES * D_EMB * 2);   // bf16 xr
    u16*   hh     = (u16*)  alloc((size_t)N_NODES * D_EMB * 2);
    u16*   hl     = (u16*)  alloc((size_t)N_NODES * D_EMB * 2);
    int*   esrcp  = (int*)  alloc((size_t)N_EDGES * 4);
    int*   rowptr = (int*)  alloc((size_t)(N_NODES + 1) * 4);
    int*   counts = (int*)  alloc((size_t)N_NODES * 4);
    int*   flag   = (int*)  alloc(256);
    float* logits = (float*)alloc((size_t)N_NODES * 4);
    int*   dhist  = (int*)  alloc(64 * 4);
    int*   nodeperm = (int*)alloc((size_t)N_NODES * 4);
    u16* wl1h = (u16*)alloc(D_EMB * D_IN  * 2);
    u16* wr1h = (u16*)alloc(D_EMB * D_IN  * 2);
    u16* wl2h = (u16*)alloc(D_EMB * D_EMB * 2);
    u16* wr2h = (u16*)alloc(D_EMB * D_EMB * 2);
    u16* wl3h = (u16*)alloc(D_EMB * D_EMB * 2);
    u16* wr3h = (u16*)alloc(D_EMB * D_EMB * 2);
    u16* a1h  = (u16*)alloc(D_EMB * D_HID * 2);
    u16* a2h  = (u16*)alloc(D_HID * D_HID * 2);
    u16* xph  = (u16*)alloc((size_t)N_NODES * D_IN * 2);
    u16* xpl  = (u16*)alloc((size_t)N_NODES * D_IN * 2);
    size_t needed = (size_t)(p - (char*)d_ws);

    if (ws_size < needed) {
        sentinel_kernel<<<(out_size + 255) / 256, 256, 0, stream>>>((float*)d_out, out_size);
        return;
    }

    u16* m1h = (u16*)xlb;
    u16* m1l = (u16*)((char*)xlb + 5120000);

    // detect + zero counts/logits/hist fused
    detect_zero_kernel<<<40, 256, 0, stream>>>(ei, (const u16*)x, flag, counts, logits, dhist);
    count_edges_kernel<<<(N_EDGES + 255) / 256, 256, 0, stream>>>(ei, flag, counts);
    scan_counts_kernel<<<1, 256, 0, stream>>>(counts, rowptr);
    fill_esrcp_kernel<<<(N_EDGES + 255) / 256, 256, 0, stream>>>(ei, flag, counts, esrcp);
    // degree-descending node order (counts[n] == rowptr[n+1] after fill)
    deg_hist_kernel<<<(N_NODES + 255) / 256, 256, 0, stream>>>(rowptr, counts, dhist);
    deg_scan_kernel<<<1, 64, 0, stream>>>(dhist);
    deg_scatter_kernel<<<(N_NODES + 255) / 256, 256, 0, stream>>>(rowptr, counts, dhist, nodeperm);

    // fused preconversion: x -> hi/lo; weights -> hi only (transposed)
    ConvJobs jobs;
    auto setjob = [&](int i, const void* s, u16* dh, u16* dl, int r, int c, int tr) {
        jobs.src[i] = s; jobs.dh[i] = dh; jobs.dl[i] = dl;
        jobs.rows[i] = r; jobs.cols[i] = c; jobs.trans[i] = tr;
    };
    setjob(0, x,     xph,  xpl,     N_NODES, D_IN, 0);
    setjob(1, Wl[0], wl1h, nullptr, D_IN,  D_EMB, 1);
    setjob(2, Wr[0], wr1h, nullptr, D_IN,  D_EMB, 1);
    setjob(3, Wl[1], wl2h, nullptr, D_EMB, D_EMB, 1);
    setjob(4, Wr[1], wr2h, nullptr, D_EMB, D_EMB, 1);
    setjob(5, Wl[2], wl3h, nullptr, D_EMB, D_EMB, 1);
    setjob(6, Wr[2], wr3h, nullptr, D_EMB, D_EMB, 1);
    setjob(7, A1,    a1h,  nullptr, D_EMB, D_HID, 1);
    setjob(8, A2,    a2h,  nullptr, D_HID, D_HID, 1);
    jobs.njobs = 9;
    jobs.cum[0] = 0;
    for (int i = 0; i < 9; i++) jobs.cum[i + 1] = jobs.cum[i] + jobs.rows[i] * jobs.cols[i];
    int ctotal = jobs.cum[9];
    convert_fused_kernel<<<(ctotal + 255) / 256, 256, 0, stream>>>(jobs, flag);

    dim3 gdual(2 * D_EMB / 128, (N_NODES + 127) / 128);   // (8, 79)
    dim3 gmlp64(D_HID / 64, (N_NODES + 63) / 64);         // (4, 157)
    int gatgrid = (N_NODES + 3) / 4;

    // layer 1
    gemm_dual_kernel<<<gdual, 256, 0, stream>>>(xph, xpl, wl1h, wr1h, xlb, xrb, N_NODES, D_EMB, D_IN);
    gat_wave_kernel<<<gatgrid, 256, 0, stream>>>(rowptr, esrcp, nodeperm, xlb, xrb, att[0], bia[0], flag, hh, hl);
    // layer 2
    gemm_dual_kernel<<<gdual, 256, 0, stream>>>(hh, hl, wl2h, wr2h, xlb, xrb, N_NODES, D_EMB, D_EMB);
    gat_wave_kernel<<<gatgrid, 256, 0, stream>>>(rowptr, esrcp, nodeperm, xlb, xrb, att[1], bia[1], flag, hh, hl);
    // layer 3
    gemm_dual_kernel<<<gdual, 256, 0, stream>>>(hh, hl, wl3h, wr3h, xlb, xrb, N_NODES, D_EMB, D_EMB);
    gat_wave_kernel<<<gatgrid, 256, 0, stream>>>(rowptr, esrcp, nodeperm, xlb, xrb, att[2], bia[2], flag, hh, hl);

    // MLP: GEMM1 stores pair; GEMM2 fuses the A3 logit GEMV via atomics
    gemm_mlp64_kernel<0><<<gmlp64, 256, 0, stream>>>(hh, hl, a1h, m1h, m1l, c1, nullptr, nullptr, flag, N_NODES, D_HID, D_EMB);
    gemm_mlp64_kernel<1><<<gmlp64, 256, 0, stream>>>(m1h, m1l, a2h, nullptr, nullptr, c2, A3, logits, flag, N_NODES, D_HID, D_HID);
    softmax_kernel<<<1, 256, 0, stream>>>(logits, (float*)d_out);
}

// Round 19
// 434.422 us; speedup vs baseline: 1.0993x; 1.0993x over previous
//
#include <hip/hip_runtime.h>
#include <hip/hip_bf16.h>

#define N_NODES 10000
#define N_EDGES 160000
#define D_IN    128
#define D_EMB   512
#define D_HID   256

typedef unsigned short u16;
typedef __attribute__((ext_vector_type(8))) short short8;
typedef __attribute__((ext_vector_type(4))) float floatx4;

__device__ __forceinline__ float bf2f(u16 u) {
    union { unsigned int i; float f; } v; v.i = ((unsigned int)u) << 16; return v.f;
}
__device__ __forceinline__ u16 f2bf(float f) {
    union { float f; unsigned int i; } v; v.f = f;
    unsigned int x = v.i;
    return (u16)((x + 0x7fffu + ((x >> 16) & 1u)) >> 16);  // RNE
}
__device__ __forceinline__ float inval(const void* p, int fp32, int idx) {
    return fp32 ? ((const float*)p)[idx] : bf2f(((const u16*)p)[idx]);
}

// async global->LDS, 16 bytes/lane; lds base must be wave-uniform.
__device__ __forceinline__ void gld_lds16(const u16* g, u16* l) {
    __builtin_amdgcn_global_load_lds((const __attribute__((address_space(1))) void*)g,
                                     (__attribute__((address_space(3))) void*)l,
                                     16, 0, 0);
}

// flag[0]: edge_index is int64-viewed-as-int32-pairs; flag[1]: floats are fp32
__device__ __forceinline__ int edge_src(const int* __restrict__ ei, int flg, int e) {
    int v = flg ? ei[2 * e] : ei[e];
    return min(max(v, 0), N_NODES - 1);
}
__device__ __forceinline__ int edge_dst(const int* __restrict__ ei, int flg, int e) {
    int v = flg ? ei[2 * N_EDGES + 2 * e] : ei[N_EDGES + e];
    return min(max(v, 0), N_NODES - 1);
}

// ---------------------------------------------------------------------------
__global__ void sentinel_kernel(float* out, int n) {
    int i = blockIdx.x * 256 + threadIdx.x;
    if (i < n) out[i] = 1.0f;   // => workspace too small
}

// detect dtypes + zero counts + zero logits, one dispatch (block 0 = census)
__global__ __launch_bounds__(256)
void detect_zero_kernel(const int* __restrict__ ei, const u16* __restrict__ xu,
                        int* flag, int* counts, float* logits) {
    int gid = blockIdx.x * 256 + threadIdx.x;
    for (int i = gid; i < N_NODES; i += gridDim.x * 256) { counts[i] = 0; logits[i] = 0.f; }
    if (blockIdx.x != 0) return;
    __shared__ int s_or[256];
    __shared__ int s_cnt[256];
    int t = threadIdx.x;
    int v = 0;
    for (int k = t; k < 4096; k += 256) v |= ei[1 + 2 * k];
    int c = 0;
    for (int k = t; k < 4096; k += 256) {
        u16 u = xu[k];
        int ex = (u >> 7) & 0xFF;
        bool plaus = (u == 0) || (ex >= 64 && ex <= 191);
        if (!plaus) c++;
    }
    s_or[t] = v; s_cnt[t] = c;
    __syncthreads();
    for (int off = 128; off > 0; off >>= 1) {
        if (t < off) { s_or[t] |= s_or[t + off]; s_cnt[t] += s_cnt[t + off]; }
        __syncthreads();
    }
    if (t == 0) {
        flag[0] = (s_or[0] == 0) ? 1 : 0;
        flag[1] = (s_cnt[0] > 256) ? 1 : 0;
    }
}

// ---------------------------------------------------------------------------
// Fused preconversion; dl == nullptr -> hi only.
// ---------------------------------------------------------------------------
struct ConvJobs {
    const void* src[10];
    u16* dh[10];
    u16* dl[10];
    int rows[10], cols[10], trans[10];
    int cum[11];
    int njobs;
};

__global__ __launch_bounds__(256)
void convert_fused_kernel(ConvJobs jobs, const int* __restrict__ flag) {
    int idx = blockIdx.x * 256 + threadIdx.x;
    if (idx >= jobs.cum[jobs.njobs]) return;
    int fp32 = flag[1];
    int jb = 0;
    while (idx >= jobs.cum[jb + 1]) jb++;
    int local = idx - jobs.cum[jb];
    float v = inval(jobs.src[jb], fp32, local);
    u16 hi = f2bf(v);
    int o;
    if (jobs.trans[jb]) {
        int r = local / jobs.cols[jb], c = local % jobs.cols[jb];
        o = c * jobs.rows[jb] + r;
    } else o = local;
    jobs.dh[jb][o] = hi;
    if (jobs.dl[jb]) jobs.dl[jb][o] = f2bf(v - bf2f(hi));
}

// ---------------------------------------------------------------------------
// CSR build
// ---------------------------------------------------------------------------
__global__ void count_edges_kernel(const int* __restrict__ ei, const int* __restrict__ flag,
                                   int* counts) {
    int e = blockIdx.x * 256 + threadIdx.x;
    if (e < N_EDGES) atomicAdd(&counts[edge_dst(ei, flag[0], e)], 1);
}

__global__ __launch_bounds__(256)
void scan_counts_kernel(int* counts, int* rowptr) {
    __shared__ int part[256];
    int tid = threadIdx.x;
    const int CH = 40;
    int base = tid * CH;
    int loc[CH];
    int s = 0;
    #pragma unroll
    for (int i = 0; i < CH; i++) {
        int idx = base + i;
        int c = (idx < N_NODES) ? counts[idx] : 0;
        loc[i] = s; s += c;
    }
    part[tid] = s;
    __syncthreads();
    for (int off = 1; off < 256; off <<= 1) {
        int v = part[tid];
        int add = (tid >= off) ? part[tid - off] : 0;
        __syncthreads();
        part[tid] = v + add;
        __syncthreads();
    }
    int pre = (tid > 0) ? part[tid - 1] : 0;
    #pragma unroll
    for (int i = 0; i < CH; i++) {
        int idx = base + i;
        if (idx < N_NODES) { int v = pre + loc[i]; rowptr[idx] = v; counts[idx] = v; }
    }
    if (tid == 255) rowptr[N_NODES] = part[255];
}

__global__ void fill_esrcp_kernel(const int* __restrict__ ei, const int* __restrict__ flag,
                                  int* counts, int* esrcp) {
    int e = blockIdx.x * 256 + threadIdx.x;
    if (e < N_EDGES) {
        int flg = flag[0];
        int pos = atomicAdd(&counts[edge_dst(ei, flg, e)], 1);
        if (pos >= 0 && pos < N_EDGES) esrcp[pos] = edge_src(ei, flg, e);
    }
}

// ---------------------------------------------------------------------------
// Dual 128x128-tile GEMM, 2 MFMA passes, async global_load_lds staging,
// XOR-swizzled unpadded LDS. C0 (xl) stored bf16; C1 (xr) stored fp32.
// ---------------------------------------------------------------------------
__global__ __launch_bounds__(256)
void gemm_dual_kernel(const u16* __restrict__ Ah, const u16* __restrict__ Al,
                      const u16* __restrict__ B0h, const u16* __restrict__ B1h,
                      u16* __restrict__ C0, float* __restrict__ C1,
                      int M, int N, int K)
{
    __shared__ u16 sAh[128 * 32];
    __shared__ u16 sAl[128 * 32];
    __shared__ u16 sBh[128 * 32];
    int nb = N >> 7;
    int half = (int)blockIdx.x >= nb;
    int bx = half ? (blockIdx.x - nb) : blockIdx.x;
    const u16* BTh = half ? B1h : B0h;

    int tid = threadIdx.x;
    int lane = tid & 63, wv = tid >> 6;
    int l15 = lane & 15, l4 = lane >> 4;
    int wr = (wv >> 1) * 64, wc = (wv & 1) * 64;
    int m0 = blockIdx.y * 128, n0 = bx * 128;

    int i0 = tid, i1 = tid + 256;
    int r0 = i0 >> 2, b0 = i0 & 3, sb0 = b0 ^ ((r0 >> 1) & 3);
    int r1 = i1 >> 2, b1 = i1 & 3, sb1 = b1 ^ ((r1 >> 1) & 3);
    int gr0 = min(m0 + r0, M - 1), gr1 = min(m0 + r1, M - 1);
    const u16* a0p = Ah + (size_t)gr0 * K + sb0 * 8;
    const u16* a1p = Ah + (size_t)gr1 * K + sb1 * 8;
    const u16* l0p = Al + (size_t)gr0 * K + sb0 * 8;
    const u16* l1p = Al + (size_t)gr1 * K + sb1 * 8;
    const u16* bb0p = BTh + (size_t)(n0 + r0) * K + sb0 * 8;
    const u16* bb1p = BTh + (size_t)(n0 + r1) * K + sb1 * 8;
    u16* lA0 = &sAh[(size_t)(wv * 64) * 8];
    u16* lA1 = &sAh[(size_t)(256 + wv * 64) * 8];
    u16* lL0 = &sAl[(size_t)(wv * 64) * 8];
    u16* lL1 = &sAl[(size_t)(256 + wv * 64) * 8];
    u16* lB0 = &sBh[(size_t)(wv * 64) * 8];
    u16* lB1 = &sBh[(size_t)(256 + wv * 64) * 8];

    floatx4 acc[4][4];
    #pragma unroll
    for (int i = 0; i < 4; i++)
        #pragma unroll
        for (int j = 0; j < 4; j++) acc[i][j] = (floatx4){0.f, 0.f, 0.f, 0.f};

    int aoff[4], boff[4];
    #pragma unroll
    for (int i = 0; i < 4; i++) {
        int arow = wr + i * 16 + l15;
        aoff[i] = arow * 32 + ((l4 ^ ((arow >> 1) & 3)) << 3);
        int bcol = wc + i * 16 + l15;
        boff[i] = bcol * 32 + ((l4 ^ ((bcol >> 1) & 3)) << 3);
    }

    for (int kk = 0; kk < K; kk += 32) {
        __syncthreads();
        gld_lds16(a0p + kk, lA0);
        gld_lds16(a1p + kk, lA1);
        gld_lds16(l0p + kk, lL0);
        gld_lds16(l1p + kk, lL1);
        gld_lds16(bb0p + kk, lB0);
        gld_lds16(bb1p + kk, lB1);
        __syncthreads();

        short8 ah[4], al[4];
        #pragma unroll
        for (int i = 0; i < 4; i++) {
            ah[i] = *(const short8*)(&sAh[aoff[i]]);
            al[i] = *(const short8*)(&sAl[aoff[i]]);
        }
        #pragma unroll
        for (int j = 0; j < 4; j++) {
            short8 bh = *(const short8*)(&sBh[boff[j]]);
            #pragma unroll
            for (int i = 0; i < 4; i++) {
                acc[i][j] = __builtin_amdgcn_mfma_f32_16x16x32_bf16(ah[i], bh, acc[i][j], 0, 0, 0);
                acc[i][j] = __builtin_amdgcn_mfma_f32_16x16x32_bf16(al[i], bh, acc[i][j], 0, 0, 0);
            }
        }
    }

    #pragma unroll
    for (int j = 0; j < 4; j++) {
        int col = n0 + wc + j * 16 + l15;
        #pragma unroll
        for (int i = 0; i < 4; i++) {
            #pragma unroll
            for (int r = 0; r < 4; r++) {
                int row = m0 + wr + i * 16 + l4 * 4 + r;
                if (row < M) {
                    if (half) C1[(size_t)row * N + col] = acc[i][j][r];
                    else      C0[(size_t)row * N + col] = f2bf(acc[i][j][r]);
                }
            }
        }
    }
}

// ---------------------------------------------------------------------------
// MLP GEMM, 64x64 tile, async staging + swizzle, bias+leaky.
// FUSE=0: store hi/lo pair. FUSE=1: fused logit GEMV via atomics (no stores).
// (c3 dropped: softmax is shift-invariant.)
// ---------------------------------------------------------------------------
template<int FUSE>
__global__ __launch_bounds__(256)
void gemm_mlp64_kernel(const u16* __restrict__ Ah, const u16* __restrict__ Al,
                       const u16* __restrict__ BTh,
                       u16* __restrict__ Ch, u16* __restrict__ Cl,
                       const void* __restrict__ biasraw,
                       const void* __restrict__ A3raw, float* __restrict__ logits,
                       const int* __restrict__ flag,
                       int M, int N, int K)
{
    __shared__ u16 sAh[64 * 32];
    __shared__ u16 sAl[64 * 32];
    __shared__ u16 sBh[64 * 32];
    int tid = threadIdx.x;
    int lane = tid & 63, wv = tid >> 6;
    int l15 = lane & 15, l4 = lane >> 4;
    int m0 = blockIdx.y * 64, n0 = blockIdx.x * 64;

    int r = (tid >> 2), blk = tid & 3, sb = blk ^ ((r >> 1) & 3);
    int gr = min(m0 + r, M - 1);
    const u16* ap = Ah + (size_t)gr * K + sb * 8;
    const u16* lp = Al + (size_t)gr * K + sb * 8;
    const u16* bp = BTh + (size_t)(n0 + r) * K + sb * 8;
    u16* lA = &sAh[(size_t)(wv * 64) * 8];
    u16* lL = &sAl[(size_t)(wv * 64) * 8];
    u16* lB = &sBh[(size_t)(wv * 64) * 8];

    floatx4 acc[4];
    #pragma unroll
    for (int j = 0; j < 4; j++) acc[j] = (floatx4){0.f, 0.f, 0.f, 0.f};

    int arow = wv * 16 + l15;
    int aoff = arow * 32 + ((l4 ^ ((arow >> 1) & 3)) << 3);
    int boff[4];
    #pragma unroll
    for (int j = 0; j < 4; j++) {
        int bcol = j * 16 + l15;
        boff[j] = bcol * 32 + ((l4 ^ ((bcol >> 1) & 3)) << 3);
    }

    for (int kk = 0; kk < K; kk += 32) {
        __syncthreads();
        gld_lds16(ap + kk, lA);
        gld_lds16(lp + kk, lL);
        gld_lds16(bp + kk, lB);
        __syncthreads();

        short8 ah = *(const short8*)(&sAh[aoff]);
        short8 al = *(const short8*)(&sAl[aoff]);
        #pragma unroll
        for (int j = 0; j < 4; j++) {
            short8 bh = *(const short8*)(&sBh[boff[j]]);
            acc[j] = __builtin_amdgcn_mfma_f32_16x16x32_bf16(ah, bh, acc[j], 0, 0, 0);
            acc[j] = __builtin_amdgcn_mfma_f32_16x16x32_bf16(al, bh, acc[j], 0, 0, 0);
        }
    }

    const int fp32 = flag[1];
    float lsum[4] = {0.f, 0.f, 0.f, 0.f};
    #pragma unroll
    for (int j = 0; j < 4; j++) {
        int col = n0 + j * 16 + l15;
        float bv = inval(biasraw, fp32, col);
        float a3 = FUSE ? inval(A3raw, fp32, col) : 0.f;
        #pragma unroll
        for (int rr = 0; rr < 4; rr++) {
            int row = m0 + wv * 16 + l4 * 4 + rr;
            if (row < M) {
                float v = acc[j][rr] + bv;
                v = v > 0.f ? v : 0.1f * v;
                if (FUSE) {
                    lsum[rr] += v * a3;
                } else {
                    u16 hi = f2bf(v);
                    Ch[(size_t)row * N + col] = hi;
                    Cl[(size_t)row * N + col] = f2bf(v - bf2f(hi));
                }
            }
        }
    }
    if (FUSE) {
        #pragma unroll
        for (int rr = 0; rr < 4; rr++) {
            float s = lsum[rr];
            s += __shfl_xor(s, 1);
            s += __shfl_xor(s, 2);
            s += __shfl_xor(s, 4);
            s += __shfl_xor(s, 8);
            int row = m0 + wv * 16 + l4 * 4 + rr;
            if (l15 == 0 && row < M) atomicAdd(&logits[row], s);
        }
    }
}

// ---------------------------------------------------------------------------
// GATv2: wave-per-node, single-pass online softmax, edge loop unrolled x4
// (R13 structure — compiler-scheduled, no explicit prefetch).
// ---------------------------------------------------------------------------
__device__ __forceinline__ void online_update(float e, const float v[8],
                                              float& m_run, float& s_run, float acc[8])
{
    if (e > m_run) {                       // lane-uniform branch
        float sc = __expf(m_run - e);
        s_run = s_run * sc + 1.f;
        #pragma unroll
        for (int k = 0; k < 8; k++) acc[k] = acc[k] * sc + v[k];
        m_run = e;
    } else {
        float w = __expf(e - m_run);
        s_run += w;
        #pragma unroll
        for (int k = 0; k < 8; k++) acc[k] += w * v[k];
    }
}

__global__ __launch_bounds__(256)
void gat_wave_kernel(const int* __restrict__ rowptr, const int* __restrict__ esrcp,
                     const u16* __restrict__ xlb, const float* __restrict__ xr,
                     const void* __restrict__ att, const void* __restrict__ bias,
                     const int* __restrict__ flag,
                     u16* __restrict__ hh, u16* __restrict__ hl)
{
    int lane = threadIdx.x & 63, wv = threadIdx.x >> 6;
    int n = blockIdx.x * 4 + wv;
    if (n >= N_NODES) return;
    int fp32 = flag[1];
    int d0 = lane * 8;

    const float* xrr = xr + (size_t)n * D_EMB;
    float4 r0 = *(const float4*)(xrr + d0);
    float4 r1 = *(const float4*)(xrr + d0 + 4);
    float xrv[8] = {r0.x, r0.y, r0.z, r0.w, r1.x, r1.y, r1.z, r1.w};
    float attv[8];
    #pragma unroll
    for (int k = 0; k < 8; k++) attv[k] = inval(att, fp32, d0 + k);

    int beg = rowptr[n], end = rowptr[n + 1];
    float m_run = -3.4e38f, s_run = 0.f;
    float acc[8] = {0.f, 0.f, 0.f, 0.f, 0.f, 0.f, 0.f, 0.f};

    int j = beg;
    for (; j + 4 <= end; j += 4) {
        int s0 = esrcp[j], s1 = esrcp[j + 1], s2 = esrcp[j + 2], s3 = esrcp[j + 3];
        union { uint4 q; u16 us[8]; } u0, u1, u2, u3;
        u0.q = *(const uint4*)(xlb + (size_t)s0 * D_EMB + d0);
        u1.q = *(const uint4*)(xlb + (size_t)s1 * D_EMB + d0);
        u2.q = *(const uint4*)(xlb + (size_t)s2 * D_EMB + d0);
        u3.q = *(const uint4*)(xlb + (size_t)s3 * D_EMB + d0);
        float v0[8], v1[8], v2[8], v3[8];
        #pragma unroll
        for (int k = 0; k < 8; k++) {
            v0[k] = bf2f(u0.us[k]); v1[k] = bf2f(u1.us[k]);
            v2[k] = bf2f(u2.us[k]); v3[k] = bf2f(u3.us[k]);
        }
        float e0 = 0.f, e1 = 0.f, e2 = 0.f, e3 = 0.f;
        #pragma unroll
        for (int k = 0; k < 8; k++) {
            float t0 = v0[k] + xrv[k]; t0 = t0 > 0.f ? t0 : 0.2f * t0; e0 += attv[k] * t0;
            float t1 = v1[k] + xrv[k]; t1 = t1 > 0.f ? t1 : 0.2f * t1; e1 += attv[k] * t1;
            float t2 = v2[k] + xrv[k]; t2 = t2 > 0.f ? t2 : 0.2f * t2; e2 += attv[k] * t2;
            float t3 = v3[k] + xrv[k]; t3 = t3 > 0.f ? t3 : 0.2f * t3; e3 += attv[k] * t3;
        }
        #pragma unroll
        for (int o = 32; o > 0; o >>= 1) {
            e0 += __shfl_xor(e0, o);
            e1 += __shfl_xor(e1, o);
            e2 += __shfl_xor(e2, o);
            e3 += __shfl_xor(e3, o);
        }
        online_update(e0, v0, m_run, s_run, acc);
        online_update(e1, v1, m_run, s_run, acc);
        online_update(e2, v2, m_run, s_run, acc);
        online_update(e3, v3, m_run, s_run, acc);
    }
    for (; j < end; j++) {
        int s0 = esrcp[j];
        union { uint4 q; u16 us[8]; } u0;
        u0.q = *(const uint4*)(xlb + (size_t)s0 * D_EMB + d0);
        float v0[8];
        #pragma unroll
        for (int k = 0; k < 8; k++) v0[k] = bf2f(u0.us[k]);
        float e0 = 0.f;
        #pragma unroll
        for (int k = 0; k < 8; k++) {
            float t = v0[k] + xrv[k]; t = t > 0.f ? t : 0.2f * t; e0 += attv[k] * t;
        }
        #pragma unroll
        for (int o = 32; o > 0; o >>= 1) e0 += __shfl_xor(e0, o);
        online_update(e0, v0, m_run, s_run, acc);
    }

    float inv = 1.f / (s_run + 1e-16f);
    union { uint4 q; u16 us[8]; } ph, pl;
    #pragma unroll
    for (int k = 0; k < 8; k++) {
        float h = tanhf(acc[k] * inv + inval(bias, fp32, d0 + k));
        u16 hi = f2bf(h);
        ph.us[k] = hi;
        pl.us[k] = f2bf(h - bf2f(hi));
    }
    *(uint4*)(&hh[(size_t)n * D_EMB + d0]) = ph.q;
    *(uint4*)(&hl[(size_t)n * D_EMB + d0]) = pl.q;
}

// ---------------------------------------------------------------------------
__global__ __launch_bounds__(256)
void softmax_kernel(const float* __restrict__ logits, float* __restrict__ out)
{
    __shared__ float red[4];
    __shared__ float s_m, s_s;
    int tid = threadIdx.x, lane = tid & 63, wv = tid >> 6;
    float m = -3.4e38f;
    for (int i = tid; i < N_NODES; i += 256) m = fmaxf(m, logits[i]);
    #pragma unroll
    for (int o = 32; o > 0; o >>= 1) m = fmaxf(m, __shfl_down(m, o));
    if (lane == 0) red[wv] = m;
    __syncthreads();
    if (tid == 0) {
        float mm = red[0];
        for (int i = 1; i < 4; i++) mm = fmaxf(mm, red[i]);
        s_m = mm;
    }
    __syncthreads();
    float mm = s_m;
    float s = 0.f;
    for (int i = tid; i < N_NODES; i += 256) s += __expf(logits[i] - mm);
    #pragma unroll
    for (int o = 32; o > 0; o >>= 1) s += __shfl_down(s, o);
    if (lane == 0) red[wv] = s;
    __syncthreads();
    if (tid == 0) {
        float ss = 0.f;
        for (int i = 0; i < 4; i++) ss += red[i];
        s_s = ss;
    }
    __syncthreads();
    float invs = 1.f / s_s;
    for (int i = tid; i < N_NODES; i += 256) out[i] = __expf(logits[i] - mm) * invs;
}

// ---------------------------------------------------------------------------
extern "C" void kernel_launch(void* const* d_in, const int* in_sizes, int n_in,
                              void* d_out, int out_size, void* d_ws, size_t ws_size,
                              hipStream_t stream)
{
    const void* x   = d_in[0];
    const int*  ei  = (const int*)d_in[1];
    const void* Wl[3]  = {d_in[2],  d_in[6],  d_in[10]};
    const void* Wr[3]  = {d_in[3],  d_in[7],  d_in[11]};
    const void* att[3] = {d_in[4],  d_in[8],  d_in[12]};
    const void* bia[3] = {d_in[5],  d_in[9],  d_in[13]};
    const void* A1 = d_in[14];
    const void* c1 = d_in[15];
    const void* A2 = d_in[16];
    const void* c2 = d_in[17];
    const void* A3 = d_in[18];

    char* p = (char*)d_ws;
    auto alloc = [&](size_t bytes) {
        char* r = p;
        p += (bytes + 255) & ~(size_t)255;
        return r;
    };
    u16*   xlb    = (u16*)  alloc((size_t)N_NODES * D_EMB * 4);   // bf16 xl (first half) + MLP aliases
    float* xr     = (float*)alloc((size_t)N_NODES * D_EMB * 4);
    u16*   hh     = (u16*)  alloc((size_t)N_NODES * D_EMB * 2);
    u16*   hl     = (u16*)  alloc((size_t)N_NODES * D_EMB * 2);
    int*   esrcp  = (int*)  alloc((size_t)N_EDGES * 4);
    int*   rowptr = (int*)  alloc((size_t)(N_NODES + 1) * 4);
    int*   counts = (int*)  alloc((size_t)N_NODES * 4);
    int*   flag   = (int*)  alloc(256);
    float* logits = (float*)alloc((size_t)N_NODES * 4);
    u16* wl1h = (u16*)alloc(D_EMB * D_IN  * 2);
    u16* wr1h = (u16*)alloc(D_EMB * D_IN  * 2);
    u16* wl2h = (u16*)alloc(D_EMB * D_EMB * 2);
    u16* wr2h = (u16*)alloc(D_EMB * D_EMB * 2);
    u16* wl3h = (u16*)alloc(D_EMB * D_EMB * 2);
    u16* wr3h = (u16*)alloc(D_EMB * D_EMB * 2);
    u16* a1h  = (u16*)alloc(D_EMB * D_HID * 2);
    u16* a2h  = (u16*)alloc(D_HID * D_HID * 2);
    u16* xph  = (u16*)alloc((size_t)N_NODES * D_IN * 2);
    u16* xpl  = (u16*)alloc((size_t)N_NODES * D_IN * 2);
    size_t needed = (size_t)(p - (char*)d_ws);

    if (ws_size < needed) {
        sentinel_kernel<<<(out_size + 255) / 256, 256, 0, stream>>>((float*)d_out, out_size);
        return;
    }

    u16* m1h = (u16*)xlb;
    u16* m1l = (u16*)((char*)xlb + 5120000);

    // detect + zero counts + zero logits fused
    detect_zero_kernel<<<40, 256, 0, stream>>>(ei, (const u16*)x, flag, counts, logits);
    count_edges_kernel<<<(N_EDGES + 255) / 256, 256, 0, stream>>>(ei, flag, counts);
    scan_counts_kernel<<<1, 256, 0, stream>>>(counts, rowptr);
    fill_esrcp_kernel<<<(N_EDGES + 255) / 256, 256, 0, stream>>>(ei, flag, counts, esrcp);

    // fused preconversion: x -> hi/lo; weights -> hi only (transposed)
    ConvJobs jobs;
    auto setjob = [&](int i, const void* s, u16* dh, u16* dl, int r, int c, int tr) {
        jobs.src[i] = s; jobs.dh[i] = dh; jobs.dl[i] = dl;
        jobs.rows[i] = r; jobs.cols[i] = c; jobs.trans[i] = tr;
    };
    setjob(0, x,     xph,  xpl,     N_NODES, D_IN, 0);
    setjob(1, Wl[0], wl1h, nullptr, D_IN,  D_EMB, 1);
    setjob(2, Wr[0], wr1h, nullptr, D_IN,  D_EMB, 1);
    setjob(3, Wl[1], wl2h, nullptr, D_EMB, D_EMB, 1);
    setjob(4, Wr[1], wr2h, nullptr, D_EMB, D_EMB, 1);
    setjob(5, Wl[2], wl3h, nullptr, D_EMB, D_EMB, 1);
    setjob(6, Wr[2], wr3h, nullptr, D_EMB, D_EMB, 1);
    setjob(7, A1,    a1h,  nullptr, D_EMB, D_HID, 1);
    setjob(8, A2,    a2h,  nullptr, D_HID, D_HID, 1);
    jobs.njobs = 9;
    jobs.cum[0] = 0;
    for (int i = 0; i < 9; i++) jobs.cum[i + 1] = jobs.cum[i] + jobs.rows[i] * jobs.cols[i];
    int ctotal = jobs.cum[9];
    convert_fused_kernel<<<(ctotal + 255) / 256, 256, 0, stream>>>(jobs, flag);

    dim3 gdual(2 * D_EMB / 128, (N_NODES + 127) / 128);   // (8, 79)
    dim3 gmlp64(D_HID / 64, (N_NODES + 63) / 64);         // (4, 157)
    int gatgrid = (N_NODES + 3) / 4;

    // layer 1
    gemm_dual_kernel<<<gdual, 256, 0, stream>>>(xph, xpl, wl1h, wr1h, xlb, xr, N_NODES, D_EMB, D_IN);
    gat_wave_kernel<<<gatgrid, 256, 0, stream>>>(rowptr, esrcp, xlb, xr, att[0], bia[0], flag, hh, hl);
    // layer 2
    gemm_dual_kernel<<<gdual, 256, 0, stream>>>(hh, hl, wl2h, wr2h, xlb, xr, N_NODES, D_EMB, D_EMB);
    gat_wave_kernel<<<gatgrid, 256, 0, stream>>>(rowptr, esrcp, xlb, xr, att[1], bia[1], flag, hh, hl);
    // layer 3
    gemm_dual_kernel<<<gdual, 256, 0, stream>>>(hh, hl, wl3h, wr3h, xlb, xr, N_NODES, D_EMB, D_EMB);
    gat_wave_kernel<<<gatgrid, 256, 0, stream>>>(rowptr, esrcp, xlb, xr, att[2], bia[2], flag, hh, hl);

    // MLP: GEMM1 stores pair; GEMM2 fuses the A3 logit GEMV via atomics
    gemm_mlp64_kernel<0><<<gmlp64, 256, 0, stream>>>(hh, hl, a1h, m1h, m1l, c1, nullptr, nullptr, flag, N_NODES, D_HID, D_EMB);
    gemm_mlp64_kernel<1><<<gmlp64, 256, 0, stream>>>(m1h, m1l, a2h, nullptr, nullptr, c2, A3, logits, flag, N_NODES, D_HID, D_HID);
    softmax_kernel<<<1, 256, 0, stream>>>(logits, (float*)d_out);
}